// Round 3
// baseline (247.600 us; speedup 1.0000x reference)
//
#include <hip/hip_runtime.h>

// Problem constants (match reference)
constexpr int B = 8, C = 256, H = 96, W = 96;
constexpr int HW = H * W;          // 9216
constexpr int NPIX = B * HW;       // 73728
constexpr int PATCH = 21;
constexpr int HALF = PATCH / 2;    // 10
constexpr int DIL = 2;
constexpr int P2 = PATCH * PATCH;  // 441

// ---------------- Stage 1 ----------------
// D[b,y,x] = sum_c in1[b,c,y,x] * in2[b,c,y,x]
// blockDim (16,16). Each block: 64 consecutive pixels (16 lanes x float4),
// channels split 16-way across ty (16 channels each). 1152 blocks -> ~18
// waves/CU, float4 (16B) loads at full coalescing.
__global__ __launch_bounds__(256) void dot_kernel(const float* __restrict__ a,
                                                  const float* __restrict__ b,
                                                  float* __restrict__ D) {
    __shared__ float4 red[16][16];   // [ty][tx]
    const int tx = threadIdx.x;      // 0..15 : x-quad within 64-pixel tile
    const int ty = threadIdx.y;      // 0..15 : channel group
    const int blk = blockIdx.x;      // 0..1151
    const int pix0 = blk * 64;       // 64 divides HW -> never straddles b
    const int bb = pix0 / HW;
    const int hw0 = pix0 - bb * HW;  // multiple of 64 -> 16B-aligned base

    const int c0 = ty * 16;
    const float4* pa = (const float4*)(a + ((size_t)bb * C + c0) * HW + hw0) + tx;
    const float4* pb = (const float4*)(b + ((size_t)bb * C + c0) * HW + hw0) + tx;
    constexpr size_t CH_STRIDE = HW / 4;  // float4 stride between channels

    float4 acc = make_float4(0.f, 0.f, 0.f, 0.f);
    #pragma unroll 8
    for (int k = 0; k < 16; ++k) {
        float4 av = pa[k * CH_STRIDE];
        float4 bv = pb[k * CH_STRIDE];
        acc.x = fmaf(av.x, bv.x, acc.x);
        acc.y = fmaf(av.y, bv.y, acc.y);
        acc.z = fmaf(av.z, bv.z, acc.z);
        acc.w = fmaf(av.w, bv.w, acc.w);
    }
    red[ty][tx] = acc;
    __syncthreads();
    #pragma unroll
    for (int s = 8; s > 0; s >>= 1) {
        if (ty < s) {
            float4 o = red[ty + s][tx];
            float4 m = red[ty][tx];
            m.x += o.x; m.y += o.y; m.z += o.z; m.w += o.w;
            red[ty][tx] = m;
        }
        __syncthreads();
    }
    if (ty == 0) {
        ((float4*)(D + (size_t)bb * HW + hw0))[tx] = red[0][tx];
    }
}

// ---------------- Stage 2 ----------------
// out[b, py*21+px, y, x] = D[b, y+(py-10)*2, x+(px-10)*2]  (0 if OOB)
// One block per (b,p) output plane: the p->(py,px) decode is block-uniform,
// the per-element decode is a single /24, each block writes one contiguous
// 36 KB plane (float4), and reads a single 36 KB D image (L1/L2-resident).
__global__ __launch_bounds__(256) void scatter_kernel(const float* __restrict__ D,
                                                      float* __restrict__ out) {
    constexpr int W4 = W / 4;        // 24 float4s per row
    constexpr int Q = HW / 4;        // 2304 float4s per plane
    constexpr int ITER = Q / 256;    // 9 float4s per thread

    const int p  = blockIdx.x;       // 0..440
    const int bb = blockIdx.y;       // 0..7
    const int py = p / PATCH;
    const int px = p - py * PATCH;
    const int dy = (py - HALF) * DIL;
    const int dx = (px - HALF) * DIL;

    const float* Db = D + (size_t)bb * HW;
    float4* o = (float4*)(out + ((size_t)bb * P2 + p) * HW);
    const int t = threadIdx.x;

    #pragma unroll
    for (int i = 0; i < ITER; ++i) {
        int q  = t + i * 256;        // float4 index within the plane
        int y  = q / W4;             // magic-mul
        int x4 = q - y * W4;
        int sy = y + dy;
        float4 v = make_float4(0.f, 0.f, 0.f, 0.f);
        if (sy >= 0 && sy < H) {
            const float* row = Db + sy * W;
            int sx0 = x4 * 4 + dx;   // always even -> aligned float2 loads ok
            if (sx0 >= 0 && sx0 + 3 < W) {
                float2 lo = *(const float2*)(row + sx0);
                float2 hi = *(const float2*)(row + sx0 + 2);
                v = make_float4(lo.x, lo.y, hi.x, hi.y);
            } else {
                float* pv = &v.x;
                #pragma unroll
                for (int j = 0; j < 4; ++j) {
                    int sx = sx0 + j;
                    if (sx >= 0 && sx < W) pv[j] = row[sx];
                }
            }
        }
        o[q] = v;                    // wave: 64 consecutive q -> 1 KB store
    }
}

extern "C" void kernel_launch(void* const* d_in, const int* in_sizes, int n_in,
                              void* d_out, int out_size, void* d_ws, size_t ws_size,
                              hipStream_t stream) {
    const float* in1 = (const float*)d_in[0];
    const float* in2 = (const float*)d_in[1];
    float* out = (float*)d_out;
    float* D = (float*)d_ws;  // NPIX floats = 294,912 bytes

    {
        dim3 threads(16, 16);
        int blocks = NPIX / 64;  // 1152
        dot_kernel<<<blocks, threads, 0, stream>>>(in1, in2, D);
    }
    {
        dim3 grid(P2, B);        // 441 x 8 blocks, one output plane each
        scatter_kernel<<<grid, 256, 0, stream>>>(D, out);
    }
}